// Round 1
// 1737.702 us; speedup vs baseline: 1.0154x; 1.0154x over previous
//
#include <hip/hip_runtime.h>

// Sparse SGD: weights_out = weights; for i < valid_count:
//   weights_out[indices[i]] -= lr * gradients[i]  (scatter-add, duplicates accumulate)
// moments_out = moments (pass-through).
//
// Strategy (v2): invert the scatter instead of atomically pounding w_out.
//   k0: head[v] = -1 for all V vocab rows (4 MB workspace).
//   k1: for i < vc: next[i] = atomicExch(&head[indices[i]], i)
//       -> per-vocab-row linked list of gradient rows. 200K atomics on a
//          4 MB L2-resident array instead of 25.6M fp32 atomics on 512 MB.
//   k2: one streaming pass over all V rows: copy moments row, load weights
//       row, walk the row's chain applying -lr*g (fma), store w_out row.
//       All loads/stores coalesced (512 B per wave per array); zero atomics.
// Traffic ~= 2.15 GB total -> BW-roofline bound.

#define D_DIM 128

// ---------------- fast path ----------------

__global__ __launch_bounds__(256) void init_head_kernel(int* __restrict__ head,
                                                        const int V) {
    const int stride = gridDim.x * blockDim.x;
    for (int v = blockIdx.x * blockDim.x + threadIdx.x; v < V; v += stride)
        head[v] = -1;
}

__global__ __launch_bounds__(256) void build_chains_kernel(
    const int* __restrict__ indices,
    const int* __restrict__ vc_ptr,
    int* __restrict__ head,
    int* __restrict__ next) {
    const int i = blockIdx.x * blockDim.x + threadIdx.x;
    if (i < vc_ptr[0]) {
        const int row = indices[i];
        // Device-scope exch; list order is arbitrary (fp add tolerance covers it).
        next[i] = atomicExch(&head[row], i);
    }
}

__global__ __launch_bounds__(256) void fused_copy_update_kernel(
    const float* __restrict__ weights,
    const float* __restrict__ moments,
    const float* __restrict__ grads,
    const float* __restrict__ lr_ptr,
    const int* __restrict__ head,
    const int* __restrict__ next,
    float* __restrict__ w_out,
    float* __restrict__ m_out,
    const int V) {
    const float lr = lr_ptr[0];
    const int lane2 = (threadIdx.x & 63) * 2;        // 2 floats / lane, 128/row
    const int wpb = blockDim.x >> 6;                  // waves per block
    const int wave = blockIdx.x * wpb + (threadIdx.x >> 6);
    const int nwaves = gridDim.x * wpb;

    for (int row = wave; row < V; row += nwaves) {
        const size_t base = (size_t)row * D_DIM + lane2;

        // moments pass-through (streaming copy, 512 B/wave contiguous)
        const float2 m = *(const float2*)(moments + base);
        *(float2*)(m_out + base) = m;

        // weights row + chain of sparse updates
        float2 w = *(const float2*)(weights + base);
        for (int i = head[row]; i >= 0; i = next[i]) {
            const float2 g = *(const float2*)(grads + (size_t)i * D_DIM + lane2);
            w.x = fmaf(-lr, g.x, w.x);
            w.y = fmaf(-lr, g.y, w.y);
        }
        *(float2*)(w_out + base) = w;
    }
}

// ---------------- fallback (previous verified version) ----------------

__global__ void sgd_scatter_kernel(const float* __restrict__ grads,
                                   const int* __restrict__ indices,
                                   const float* __restrict__ lr_ptr,
                                   const int* __restrict__ vc_ptr,
                                   float* __restrict__ w_out) {
    const float lr = lr_ptr[0];
    const long long total = (long long)vc_ptr[0] * D_DIM;
    const long long stride = (long long)gridDim.x * blockDim.x;
    for (long long t = (long long)blockIdx.x * blockDim.x + threadIdx.x;
         t < total; t += stride) {
        const int i = (int)(t >> 7);
        const int j = (int)(t & 127);
        const long long row = (long long)indices[i];
        atomicAdd(w_out + row * D_DIM + j, -lr * grads[t]);
    }
}

extern "C" void kernel_launch(void* const* d_in, const int* in_sizes, int n_in,
                              void* d_out, int out_size, void* d_ws, size_t ws_size,
                              hipStream_t stream) {
    const float* grads   = (const float*)d_in[0];   // [N, 128] fp32
    const float* weights = (const float*)d_in[1];   // [V, 128] fp32
    const float* moments = (const float*)d_in[2];   // [V, 128] fp32
    const int*   indices = (const int*)  d_in[3];   // [N] int32
    const float* lr_ptr  = (const float*)d_in[4];   // [1] fp32
    const int*   vc_ptr  = (const int*)  d_in[5];   // [1] int (static 200000)

    const size_t VD = (size_t)in_sizes[1];          // V * 128 elements
    const int V = (int)(VD / D_DIM);
    const int N = in_sizes[0] / D_DIM;
    float* w_out = (float*)d_out;
    float* m_out = w_out + VD;

    const size_t ws_need = ((size_t)V + (size_t)N) * sizeof(int);

    if (d_ws != nullptr && ws_size >= ws_need) {
        int* head = (int*)d_ws;       // [V]
        int* next = head + V;         // [N] (only first vc entries used)

        // k0: head = -1
        init_head_kernel<<<1024, 256, 0, stream>>>(head, V);
        // k1: per-row linked lists (200K small atomics, L2-resident)
        build_chains_kernel<<<(N + 255) / 256, 256, 0, stream>>>(
            indices, vc_ptr, head, next);
        // k2: fused copy + sparse update, one wave per vocab row, grid-stride.
        // 2048 blocks x 256 = 8192 waves -> 128 rows/wave, full residency.
        fused_copy_update_kernel<<<2048, 256, 0, stream>>>(
            weights, moments, grads, lr_ptr, head, next, w_out, m_out, V);
    } else {
        // Fallback: bulk copies + atomic scatter (previous verified path).
        hipMemcpyAsync(w_out, weights, VD * sizeof(float),
                       hipMemcpyDeviceToDevice, stream);
        hipMemcpyAsync(m_out, moments, VD * sizeof(float),
                       hipMemcpyDeviceToDevice, stream);
        sgd_scatter_kernel<<<8192, 256, 0, stream>>>(grads, indices, lr_ptr,
                                                     vc_ptr, w_out);
    }
}